// Round 9
// baseline (1512.090 us; speedup 1.0000x reference)
//
#include <hip/hip_runtime.h>

#define NA 10000
#define NE 320000

typedef short short8 __attribute__((ext_vector_type(8)));
typedef unsigned short us4 __attribute__((ext_vector_type(4)));
typedef float f32x4 __attribute__((ext_vector_type(4)));

__device__ __forceinline__ float silu_f(float v) { return v / (1.0f + __expf(-v)); }

__device__ __forceinline__ void split_bf16(float x, unsigned short& h, unsigned short& l)
{
    unsigned int u = __float_as_uint(x);
    h = (unsigned short)(u >> 16);
    float hf = __uint_as_float((unsigned int)h << 16);
    unsigned int ul = __float_as_uint(x - hf) + 0x8000u;
    l = (unsigned short)(ul >> 16);
}

// ---------------- init ----------------------------------------------------------
__global__ __launch_bounds__(256) void k_init(
    const int* __restrict__ Z, const int* __restrict__ idx_m,
    const float* __restrict__ emb, const float* __restrict__ e_field,
    float* __restrict__ q, float* __restrict__ mu,
    float* __restrict__ Eat, int* __restrict__ counts, int* __restrict__ cursor)
{
    int gid = blockIdx.x * 256 + threadIdx.x;
    if (gid < NA * 384) mu[gid] = 0.0f;
    if (gid < NA * 128) {
        int i = gid >> 7, f = gid & 127;
        q[gid] = emb[Z[i] * 128 + f];
    }
    if (gid < NA * 3) {
        int i = gid / 3, d = gid - i * 3;
        Eat[gid] = e_field[idx_m[i] * 3 + d];
    }
    if (gid < NA) { counts[gid] = 0; cursor[gid] = 0; }
}

// ---------------- histogram idx_i -----------------------------------------------
__global__ __launch_bounds__(256) void k_count(
    const int* __restrict__ idx_i, int* __restrict__ counts)
{
    int e = blockIdx.x * 256 + threadIdx.x;
    if (e < NE) atomicAdd(&counts[idx_i[e]], 1);
}

// ---------------- exclusive scan -------------------------------------------------
__global__ __launch_bounds__(256) void k_scan(const int* __restrict__ counts,
                                              int* __restrict__ rowptr)
{
    __shared__ int part[256];
    int tid = threadIdx.x;
    const int CH = (NA + 255) / 256;
    int base = tid * CH;
    int s = 0;
    for (int i2 = 0; i2 < CH; i2++) {
        int idx = base + i2;
        if (idx < NA) s += counts[idx];
    }
    part[tid] = s;
    __syncthreads();
    for (int ofs = 1; ofs < 256; ofs <<= 1) {
        int v = part[tid];
        int add = (tid >= ofs) ? part[tid - ofs] : 0;
        __syncthreads();
        part[tid] = v + add;
        __syncthreads();
    }
    int run = (tid > 0) ? part[tid - 1] : 0;
    for (int i2 = 0; i2 < CH; i2++) {
        int idx = base + i2;
        if (idx < NA) { rowptr[idx] = run; run += counts[idx]; }
        else if (idx == NA) rowptr[NA] = run;
    }
}

// ---------------- geometry + scatter into CSR order -----------------------------
__global__ __launch_bounds__(256) void k_geom_scatter(
    const float* __restrict__ r_ij, const int* __restrict__ idx_i,
    const int* __restrict__ idx_j, const int* __restrict__ rowptr,
    int* __restrict__ cursor, float* __restrict__ phi_s,
    float4* __restrict__ df_s, int* __restrict__ j_s)
{
    int e = blockIdx.x * 256 + threadIdx.x;
    if (e >= NE) return;
    float x = r_ij[e*3+0], y = r_ij[e*3+1], z = r_ij[e*3+2];
    float d = sqrtf(x*x + y*y + z*z);
    float inv = 1.0f / d;
    float fc = (d < 5.0f) ? 0.5f * (__cosf(d * 0.628318530717958648f) + 1.0f) : 0.0f;
    int i = idx_i[e];
    int pos = rowptr[i] + atomicAdd(&cursor[i], 1);
    float4 dv; dv.x = x*inv; dv.y = y*inv; dv.z = z*inv; dv.w = fc;
    df_s[pos] = dv;
    j_s[pos] = idx_j[e];
    const float invw = 19.0f / 5.0f;
    float ph[20];
    #pragma unroll
    for (int k = 0; k < 20; k++) {
        float off = (5.0f / 19.0f) * (float)k;
        float u = (d - off) * invw;
        ph[k] = __expf(-0.5f * u * u) * fc;
    }
    #pragma unroll
    for (int c = 0; c < 5; c++) {
        float4 pv; pv.x = ph[c*4]; pv.y = ph[c*4+1]; pv.z = ph[c*4+2]; pv.w = ph[c*4+3];
        *(float4*)(phi_s + (size_t)pos*20 + c*4) = pv;
    }
}

// ---------------- weight prep: hi/lo bf16 split, MFMA-fragment-linear -----------
struct WDesc { const float* src; unsigned short* dh; unsigned short* dl; int K; int N; };
struct WPack { WDesc w[24]; };

__global__ __launch_bounds__(256) void k_wprep(WPack P)
{
    WDesc d = P.w[blockIdx.y];
    int kBlks = d.K >> 5, nStrips = d.N >> 4;
    int total = nStrips * kBlks * 64;
    int g = blockIdx.x * 256 + threadIdx.x;
    if (g >= total) return;
    int lane = g & 63, rem = g >> 6;
    int kb = rem % kBlks, sIdx = rem / kBlks;
    int m16 = lane & 15, quad = lane >> 4;
    int n = sIdx * 16 + m16;
    int kbase = kb * 32 + quad * 8;
    size_t dofs = (size_t)g * 8;
    #pragma unroll
    for (int jj = 0; jj < 8; jj++) {
        unsigned short h, l;
        split_bf16(d.src[(size_t)(kbase + jj) * d.N + n], h, l);
        d.dh[dofs + jj] = h;
        d.dl[dofs + jj] = l;
    }
}

// ---------------- filter weight prep: W(20) + bias(k=20), pad K=32 --------------
// dest layout identical to k_wprep fragment-linear: [(t*24 + strip)*64 + lane]*8+j
__global__ __launch_bounds__(256) void k_wfprep(
    const float* __restrict__ filt_W, const float* __restrict__ filt_b,
    unsigned short* __restrict__ wfh, unsigned short* __restrict__ wfl)
{
    int g = blockIdx.x * 256 + threadIdx.x;
    if (g >= 3 * 24 * 64) return;
    int lane = g & 63, rem = g >> 6;
    int st = rem % 24, t = rem / 24;
    int col = lane & 15, quad = lane >> 4;
    int tcol = t * 384 + st * 16 + col;
    size_t dofs = (size_t)g * 8;
    #pragma unroll
    for (int j = 0; j < 8; j++) {
        int k = quad * 8 + j;
        float v = 0.0f;
        if (k < 20) v = filt_W[k * 1152 + tcol];
        else if (k == 20) v = filt_b[tcol];
        unsigned short hh, ll;
        split_bf16(v, hh, ll);
        wfh[dofs + j] = hh;
        wfl[dofs + j] = ll;
    }
}

// ---------------- MFMA GEMM (bf16 split-3), 64x64 tile --------------------------
template<int ACT>
__global__ __launch_bounds__(256) void k_gmm2(
    const float* __restrict__ A,
    const unsigned short* __restrict__ Bh, const unsigned short* __restrict__ Bl,
    const float* __restrict__ bias, float* __restrict__ C,
    int M, int K, int N)
{
    __shared__ unsigned short Ahs[64 * 40];
    __shared__ unsigned short Als[64 * 40];
    int tid = threadIdx.x, lane = tid & 63, wv = tid >> 6;
    int i0 = blockIdx.x * 64, n0 = blockIdx.y * 64;
    int m16 = lane & 15, quad = lane >> 4;
    int kBlks = K >> 5;
    int sIdx = blockIdx.y * 4 + wv;

    f32x4 acc[4];
    #pragma unroll
    for (int a = 0; a < 4; a++) acc[a] = 0.0f;

    for (int kb = 0; kb < kBlks; kb++) {
        int k0 = kb << 5;
        __syncthreads();
        #pragma unroll
        for (int s = 0; s < 2; s++) {
            int idx = s * 256 + tid;
            int r = idx >> 3, c4 = (idx & 7) << 2;
            float4 v = {0.f, 0.f, 0.f, 0.f};
            if (i0 + r < M) v = *(const float4*)(A + (size_t)(i0 + r) * K + k0 + c4);
            unsigned short h0,l0,h1,l1,h2,l2,h3,l3;
            split_bf16(v.x, h0, l0); split_bf16(v.y, h1, l1);
            split_bf16(v.z, h2, l2); split_bf16(v.w, h3, l3);
            us4 hv = {h0, h1, h2, h3}, lv = {l0, l1, l2, l3};
            *(us4*)(Ahs + r * 40 + c4) = hv;
            *(us4*)(Als + r * 40 + c4) = lv;
        }
        __syncthreads();
        size_t bofs = (((size_t)sIdx * kBlks + kb) * 64 + lane) * 8;
        short8 bh = *(const short8*)(Bh + bofs);
        short8 bl = *(const short8*)(Bl + bofs);
        #pragma unroll
        for (int tm = 0; tm < 4; tm++) {
            short8 ah = *(const short8*)(Ahs + (tm * 16 + m16) * 40 + quad * 8);
            short8 al = *(const short8*)(Als + (tm * 16 + m16) * 40 + quad * 8);
            acc[tm] = __builtin_amdgcn_mfma_f32_16x16x32_bf16(ah, bh, acc[tm], 0, 0, 0);
            acc[tm] = __builtin_amdgcn_mfma_f32_16x16x32_bf16(ah, bl, acc[tm], 0, 0, 0);
            acc[tm] = __builtin_amdgcn_mfma_f32_16x16x32_bf16(al, bh, acc[tm], 0, 0, 0);
        }
    }
    int col = n0 + wv * 16 + m16;
    float bv = bias ? bias[col] : 0.0f;
    #pragma unroll
    for (int tm = 0; tm < 4; tm++) {
        #pragma unroll
        for (int r = 0; r < 4; r++) {
            int row = i0 + tm * 16 + quad * 4 + r;
            if (row < M) {
                float v = acc[tm][r] + bv;
                if (ACT) v = silu_f(v);
                C[(size_t)row * N + col] = v;
            }
        }
    }
}

// ---------------- fused MLP with prologue/epilogue variants ----------------------
template<int K1, int N2, int PRO, int EPI>
__global__ __launch_bounds__(256, 2) void k_mlp(
    const float* __restrict__ A, const float* __restrict__ mumix,
    const unsigned short* __restrict__ B1h, const unsigned short* __restrict__ B1l,
    const float* __restrict__ b1,
    const unsigned short* __restrict__ B2h, const unsigned short* __restrict__ B2l,
    const float* __restrict__ b2,
    float* __restrict__ C,
    const float* __restrict__ av, const float* __restrict__ Eat,
    float* __restrict__ qRW, float* __restrict__ muRW,
    float* __restrict__ outPk, int last, int M)
{
    const int KB1 = K1 / 32;
    const int S2  = N2 / 64;
    __shared__ unsigned short A1h[32 * 40];
    __shared__ unsigned short A1l[32 * 40];
    __shared__ unsigned short Hh[32 * 136];
    __shared__ unsigned short Hl[32 * 136];
    __shared__ float Ys[EPI == 2 ? 32 * 384 : 1];

    int tid = threadIdx.x, lane = tid & 63, wv = tid >> 6;
    int i0 = blockIdx.x * 32;
    int m16 = lane & 15, quad = lane >> 4;

    f32x4 acc1[2][2];
    #pragma unroll
    for (int s = 0; s < 2; s++)
        #pragma unroll
        for (int tm = 0; tm < 2; tm++) acc1[s][tm] = 0.0f;

    for (int kb = 0; kb < KB1; kb++) {
        int k0 = kb << 5;
        __syncthreads();
        {
            int r = tid >> 3, c4 = (tid & 7) << 2;
            int row = i0 + r;
            float4 v = {0.f, 0.f, 0.f, 0.f};
            if (row < M) {
                if (PRO == 0) {
                    v = *(const float4*)(A + (size_t)row * K1 + k0 + c4);
                } else {
                    int g = k0 + c4;
                    if (g < 128) {
                        v = *(const float4*)(A + (size_t)row * 128 + g);
                    } else {
                        int f = g - 128;
                        float4 v0 = *(const float4*)(mumix + ((size_t)row*3 + 0)*256 + f);
                        float4 v1 = *(const float4*)(mumix + ((size_t)row*3 + 1)*256 + f);
                        float4 v2 = *(const float4*)(mumix + ((size_t)row*3 + 2)*256 + f);
                        v.x = sqrtf(v0.x*v0.x + v1.x*v1.x + v2.x*v2.x + 1e-8f);
                        v.y = sqrtf(v0.y*v0.y + v1.y*v1.y + v2.y*v2.y + 1e-8f);
                        v.z = sqrtf(v0.z*v0.z + v1.z*v1.z + v2.z*v2.z + 1e-8f);
                        v.w = sqrtf(v0.w*v0.w + v1.w*v1.w + v2.w*v2.w + 1e-8f);
                    }
                }
            }
            unsigned short h0,l0,h1,l1,h2,l2,h3,l3;
            split_bf16(v.x, h0, l0); split_bf16(v.y, h1, l1);
            split_bf16(v.z, h2, l2); split_bf16(v.w, h3, l3);
            us4 hv = {h0, h1, h2, h3}, lv = {l0, l1, l2, l3};
            *(us4*)(A1h + r * 40 + c4) = hv;
            *(us4*)(A1l + r * 40 + c4) = lv;
        }
        __syncthreads();
        #pragma unroll
        for (int tm = 0; tm < 2; tm++) {
            short8 ah = *(const short8*)(A1h + (tm * 16 + m16) * 40 + quad * 8);
            short8 al = *(const short8*)(A1l + (tm * 16 + m16) * 40 + quad * 8);
            #pragma unroll
            for (int s = 0; s < 2; s++) {
                int sIdx = wv * 2 + s;
                size_t bofs = (((size_t)sIdx * KB1 + kb) * 64 + lane) * 8;
                short8 bh = *(const short8*)(B1h + bofs);
                short8 bl = *(const short8*)(B1l + bofs);
                acc1[s][tm] = __builtin_amdgcn_mfma_f32_16x16x32_bf16(ah, bh, acc1[s][tm], 0, 0, 0);
                acc1[s][tm] = __builtin_amdgcn_mfma_f32_16x16x32_bf16(ah, bl, acc1[s][tm], 0, 0, 0);
                acc1[s][tm] = __builtin_amdgcn_mfma_f32_16x16x32_bf16(al, bh, acc1[s][tm], 0, 0, 0);
            }
        }
    }
    __syncthreads();
    #pragma unroll
    for (int s = 0; s < 2; s++) {
        int col = wv * 32 + s * 16 + m16;
        float bb = b1[col];
        #pragma unroll
        for (int tm = 0; tm < 2; tm++) {
            #pragma unroll
            for (int r = 0; r < 4; r++) {
                int row = tm * 16 + quad * 4 + r;
                float v = silu_f(acc1[s][tm][r] + bb);
                unsigned short h, l;
                split_bf16(v, h, l);
                Hh[row * 136 + col] = h;
                Hl[row * 136 + col] = l;
            }
        }
    }
    __syncthreads();

    f32x4 acc2[S2][2];
    #pragma unroll
    for (int s = 0; s < S2; s++)
        #pragma unroll
        for (int tm = 0; tm < 2; tm++) acc2[s][tm] = 0.0f;

    #pragma unroll
    for (int kb = 0; kb < 4; kb++) {
        short8 ah[2], al[2];
        #pragma unroll
        for (int tm = 0; tm < 2; tm++) {
            ah[tm] = *(const short8*)(Hh + (tm * 16 + m16) * 136 + kb * 32 + quad * 8);
            al[tm] = *(const short8*)(Hl + (tm * 16 + m16) * 136 + kb * 32 + quad * 8);
        }
        #pragma unroll
        for (int s = 0; s < S2; s++) {
            int sIdx = wv * S2 + s;
            size_t bofs = (((size_t)sIdx * 4 + kb) * 64 + lane) * 8;
            short8 bh = *(const short8*)(B2h + bofs);
            short8 bl = *(const short8*)(B2l + bofs);
            #pragma unroll
            for (int tm = 0; tm < 2; tm++) {
                acc2[s][tm] = __builtin_amdgcn_mfma_f32_16x16x32_bf16(ah[tm], bh, acc2[s][tm], 0, 0, 0);
                acc2[s][tm] = __builtin_amdgcn_mfma_f32_16x16x32_bf16(ah[tm], bl, acc2[s][tm], 0, 0, 0);
                acc2[s][tm] = __builtin_amdgcn_mfma_f32_16x16x32_bf16(al[tm], bh, acc2[s][tm], 0, 0, 0);
            }
        }
    }

    if (EPI == 0) {
        #pragma unroll
        for (int s = 0; s < S2; s++) {
            int col = (wv * S2 + s) * 16 + m16;
            float bb = b2 ? b2[col] : 0.0f;
            #pragma unroll
            for (int tm = 0; tm < 2; tm++) {
                #pragma unroll
                for (int r = 0; r < 4; r++) {
                    int row = i0 + tm * 16 + quad * 4 + r;
                    if (row < M) C[(size_t)row * N2 + col] = acc2[s][tm][r] + bb;
                }
            }
        }
    } else if (EPI == 1) {
        #pragma unroll
        for (int s = 0; s < S2; s++) {
            int col = (wv * S2 + s) * 16 + m16;
            float bb = b2[col];
            #pragma unroll
            for (int tm = 0; tm < 2; tm++) {
                #pragma unroll
                for (int r = 0; r < 4; r++) {
                    int row = i0 + tm * 16 + quad * 4 + r;
                    if (row < M) {
                        float as = acc2[s][tm][r] + bb;
                        float E0 = Eat[row*3+0], E1 = Eat[row*3+1], E2 = Eat[row*3+2];
                        size_t b0 = ((size_t)row*3 + 0)*128 + col;
                        size_t b1o = ((size_t)row*3 + 1)*128 + col;
                        size_t b2o = ((size_t)row*3 + 2)*128 + col;
                        float a0 = av[b0], a1 = av[b1o], a2 = av[b2o];
                        float dot = a0*E0 + a1*E1 + a2*E2;
                        muRW[b0] += as*E0 - dot*a0;
                        muRW[b1o] += as*E1 - dot*a1;
                        muRW[b2o] += as*E2 - dot*a2;
                    }
                }
            }
        }
    } else {
        #pragma unroll
        for (int s = 0; s < S2; s++) {
            int col = (wv * S2 + s) * 16 + m16;
            float bb = b2[col];
            #pragma unroll
            for (int tm = 0; tm < 2; tm++) {
                #pragma unroll
                for (int r = 0; r < 4; r++) {
                    int row = tm * 16 + quad * 4 + r;
                    Ys[row * 384 + col] = acc2[s][tm][r] + bb;
                }
            }
        }
        __syncthreads();
        int f = tid & 127;
        #pragma unroll
        for (int it = 0; it < 16; it++) {
            int row = (tid >> 7) + it * 2;
            int i = i0 + row;
            if (i < M) {
                float yq  = Ys[row * 384 + f];
                float ym  = Ys[row * 384 + 128 + f];
                float yqm = Ys[row * 384 + 256 + f];
                float sdot = 0.0f;
                float W[3];
                #pragma unroll
                for (int d = 0; d < 3; d++) {
                    float Vd = mumix[((size_t)i*3 + d)*256 + f];
                    W[d]     = mumix[((size_t)i*3 + d)*256 + 128 + f];
                    sdot += Vd * W[d];
                }
                float qn = qRW[(size_t)i*128 + f] + yq + yqm * sdot;
                qRW[(size_t)i*128 + f] = qn;
                float mun[3];
                #pragma unroll
                for (int d = 0; d < 3; d++) {
                    size_t mo = ((size_t)i*3 + d)*128 + f;
                    mun[d] = muRW[mo] + ym * W[d];
                    muRW[mo] = mun[d];
                }
                if (last) {
                    outPk[(size_t)i*512 + f] = qn;
                    #pragma unroll
                    for (int d = 0; d < 3; d++)
                        outPk[(size_t)i*512 + 128 + d*128 + f] = mun[d];
                }
            }
        }
    }
}

// ---------------- edge aggregation: MFMA filter dots, atom-centric --------------
// One wave per (atom, half). CSR row in 16-edge chunks. A = phi (fcut-folded,
// k=20 carries fcut so bias folds in via W row 20). 12 strips x 3 split-MFMAs.
// Gather-accumulate runs in MFMA C-layout (lane: col=lane&15, edges quad*4+r);
// cross-quad __shfl_xor reduce once per atom. No LDS, no atomics.
__global__ __launch_bounds__(64) void k_edgeM(
    int t, const float* __restrict__ phi_s, const float4* __restrict__ df_s,
    const int* __restrict__ j_s, const int* __restrict__ rowptr,
    const float* __restrict__ x, const float* __restrict__ mu_in,
    const unsigned short* __restrict__ wfh, const unsigned short* __restrict__ wfl,
    float* __restrict__ q, float* __restrict__ mu_out)
{
    int lane = threadIdx.x;
    int ia = blockIdx.x >> 1;
    int h  = blockIdx.x & 1;
    int col = lane & 15, quad = lane >> 4;

    int p0 = rowptr[ia], p1 = rowptr[ia + 1];

    float accq[4] = {};
    float accd[3][4] = {};

    for (int pb = p0; pb < p1; pb += 16) {
        // ---- A fragment: 16 edges x K32 (phi*fc at k<20, fc at k=20) ----
        int e = pb + col;
        bool val = (e < p1);
        int ec = val ? e : (p1 - 1);
        float av[8] = {0,0,0,0,0,0,0,0};
        if (val) {
            const float* pr = phi_s + (size_t)ec * 20;
            if (quad == 0) {
                float4 a = *(const float4*)(pr);
                float4 b = *(const float4*)(pr + 4);
                av[0]=a.x; av[1]=a.y; av[2]=a.z; av[3]=a.w;
                av[4]=b.x; av[5]=b.y; av[6]=b.z; av[7]=b.w;
            } else if (quad == 1) {
                float4 a = *(const float4*)(pr + 8);
                float4 b = *(const float4*)(pr + 12);
                av[0]=a.x; av[1]=a.y; av[2]=a.z; av[3]=a.w;
                av[4]=b.x; av[5]=b.y; av[6]=b.z; av[7]=b.w;
            } else if (quad == 2) {
                float4 a = *(const float4*)(pr + 16);
                av[0]=a.x; av[1]=a.y; av[2]=a.z; av[3]=a.w;
                av[4]=df_s[ec].w;               // k=20 -> fcut (bias row)
            }
            // quad 3: all zero (k=24..31 pad)
        }
        short8 ah, al;
        #pragma unroll
        for (int j = 0; j < 8; j++) {
            unsigned short hh, ll;
            split_bf16(av[j], hh, ll);
            ah[j] = (short)hh; al[j] = (short)ll;
        }

        // ---- filter dots via MFMA: 3 channels x 4 strips ----
        f32x4 dt[3][4];
        #pragma unroll
        for (int c = 0; c < 3; c++) {
            #pragma unroll
            for (int s = 0; s < 4; s++) {
                int st = c * 8 + h * 4 + s;
                size_t bo = (((size_t)(t * 24 + st)) * 64 + lane) * 8;
                short8 bh = *(const short8*)(wfh + bo);
                short8 bl = *(const short8*)(wfl + bo);
                f32x4 d = {0.f, 0.f, 0.f, 0.f};
                d = __builtin_amdgcn_mfma_f32_16x16x32_bf16(ah, bh, d, 0, 0, 0);
                d = __builtin_amdgcn_mfma_f32_16x16x32_bf16(ah, bl, d, 0, 0, 0);
                d = __builtin_amdgcn_mfma_f32_16x16x32_bf16(al, bh, d, 0, 0, 0);
                dt[c][s] = d;
            }
        }

        // ---- gather + accumulate: lane owns edges pb + quad*4 + r ----
        #pragma unroll
        for (int r = 0; r < 4; r++) {
            int pe = pb + quad * 4 + r;
            if (pe > p1 - 1) pe = p1 - 1;     // padded rows have dt==0
            int j = j_s[pe];
            float4 dfr = df_s[pe];
            size_t xb = (size_t)j * 384 + h * 64 + col;
            size_t mb = (size_t)j * 384 + h * 64 + col;   // mu rows: (j*3+d)*128
            #pragma unroll
            for (int s = 0; s < 4; s++) {
                int o = s * 16;
                float xq  = x[xb + o];
                float xr_ = x[xb + 128 + o];
                float xm  = x[xb + 256 + o];
                float m0  = mu_in[mb + o];
                float m1  = mu_in[mb + 128 + o];
                float m2  = mu_in[mb + 256 + o];
                accq[s]    += dt[0][s][r] * xq;
                float xxr = dt[1][s][r] * xr_;
                float xxm = dt[2][s][r] * xm;
                accd[0][s] += xxr * dfr.x + xxm * m0;
                accd[1][s] += xxr * dfr.y + xxm * m1;
                accd[2][s] += xxr * dfr.z + xxm * m2;
            }
        }
    }

    // ---- cross-quad reduction (each (col,strip) summed over 4 quads) ----
    #pragma unroll
    for (int s = 0; s < 4; s++) {
        accq[s] += __shfl_xor(accq[s], 16);
        accq[s] += __shfl_xor(accq[s], 32);
        #pragma unroll
        for (int d = 0; d < 3; d++) {
            accd[d][s] += __shfl_xor(accd[d][s], 16);
            accd[d][s] += __shfl_xor(accd[d][s], 32);
        }
    }
    if (quad == 0) {
        #pragma unroll
        for (int s = 0; s < 4; s++) {
            size_t qo = (size_t)ia * 128 + h * 64 + s * 16 + col;
            q[qo] += accq[s];
            #pragma unroll
            for (int d = 0; d < 3; d++) {
                size_t mo = ((size_t)ia * 3 + d) * 128 + h * 64 + s * 16 + col;
                mu_out[mo] = mu_in[mo] + accd[d][s];
            }
        }
    }
}

extern "C" void kernel_launch(void* const* d_in, const int* in_sizes, int n_in,
                              void* d_out, int out_size, void* d_ws, size_t ws_size,
                              hipStream_t stream)
{
    const int*   Z       = (const int*)d_in[0];
    const float* r_ij    = (const float*)d_in[1];
    const int*   idx_i   = (const int*)d_in[2];
    const int*   idx_j   = (const int*)d_in[3];
    const int*   idx_m   = (const int*)d_in[4];
    const float* e_field = (const float*)d_in[5];
    const float* emb     = (const float*)d_in[6];
    const float* filt_W  = (const float*)d_in[7];
    const float* filt_b  = (const float*)d_in[8];
    const float* iW1     = (const float*)d_in[9];
    const float* ib1     = (const float*)d_in[10];
    const float* iW2     = (const float*)d_in[11];
    const float* ib2     = (const float*)d_in[12];
    const float* sW1     = (const float*)d_in[13];
    const float* sb1     = (const float*)d_in[14];
    const float* sW2     = (const float*)d_in[15];
    const float* sb2     = (const float*)d_in[16];
    const float* vW      = (const float*)d_in[17];
    const float* mmW     = (const float*)d_in[18];
    const float* mW1     = (const float*)d_in[19];
    const float* mb1     = (const float*)d_in[20];
    const float* mW2     = (const float*)d_in[21];
    const float* mb2     = (const float*)d_in[22];
    float* out = (float*)d_out;

    float* base = (float*)d_ws;
    size_t off = 0;
    auto alloc = [&](size_t n) { float* p = base + off; off += (n + 255) & ~(size_t)255; return p; };
    float* q     = alloc((size_t)NA*128);
    float* mu_a  = alloc((size_t)NA*384);
    float* mu_b  = alloc((size_t)NA*384);
    float* s384  = alloc((size_t)NA*384);   // x, then a_v
    float* mumix = alloc((size_t)NA*768);
    float* Eat   = alloc((size_t)NA*3);
    float* phi_s = alloc((size_t)NE*20);
    float4* df_s = (float4*)alloc((size_t)NE*4);
    int* rowptr  = (int*)alloc(NA + 1);
    int* counts  = (int*)alloc(NA);
    int* cursor  = (int*)alloc(NA);
    int* j_s     = (int*)alloc(NE);
    unsigned short* wth = (unsigned short*)alloc(344064 + 256);
    unsigned short* wtl = (unsigned short*)alloc(344064 + 256);
    unsigned short* wfh = (unsigned short*)alloc(3*24*64*8/2 + 256);  // 36864 ushorts
    unsigned short* wfl = (unsigned short*)alloc(3*24*64*8/2 + 256);
    (void)ws_size; (void)in_sizes; (void)n_in; (void)out_size;

    WPack P;
    size_t woff = 0;
    unsigned short* WH[3][8];
    unsigned short* WL[3][8];
    int nw = 0;
    auto reg = [&](const float* src, int K, int N, int t, int slot) {
        P.w[nw].src = src; P.w[nw].dh = wth + woff; P.w[nw].dl = wtl + woff;
        P.w[nw].K = K; P.w[nw].N = N;
        WH[t][slot] = wth + woff; WL[t][slot] = wtl + woff;
        woff += (size_t)K * N; nw++;
    };
    for (int t = 0; t < 3; t++) {
        reg(iW1 + t*128*128, 128, 128, t, 0);
        reg(iW2 + t*128*384, 128, 384, t, 1);
        reg(sW1 + t*128*128, 128, 128, t, 2);
        reg(sW2 + t*128*128, 128, 128, t, 3);
        reg(vW  + t*128*128, 128, 128, t, 4);
        reg(mmW + t*128*256, 128, 256, t, 5);
        reg(mW1 + t*256*128, 256, 128, t, 6);
        reg(mW2 + t*128*384, 128, 384, t, 7);
    }

    k_wprep       <<<dim3(24, 24),          256, 0, stream>>>(P);
    k_wfprep      <<<18,                    256, 0, stream>>>(filt_W, filt_b, wfh, wfl);
    k_init        <<<(NA*384 + 255)/256,    256, 0, stream>>>(Z, idx_m, emb, e_field, q, mu_a, Eat, counts, cursor);
    k_count       <<<(NE + 255)/256,        256, 0, stream>>>(idx_i, counts);
    k_scan        <<<1,                     256, 0, stream>>>(counts, rowptr);
    k_geom_scatter<<<(NE + 255)/256,        256, 0, stream>>>(r_ij, idx_i, idx_j, rowptr, cursor,
                                                              phi_s, df_s, j_s);

    const int G32   = (NA + 31) / 32;       // 313
    const int G64x3 = (NA*3 + 63) / 64;     // 469
    float* mu_cur = mu_a;
    float* mu_nxt = mu_b;
    for (int t = 0; t < 3; t++) {
        // Interaction MLP: x = silu(q@iW1+b1)@iW2+b2
        k_mlp<128,384,0,0><<<G32, 256, 0, stream>>>(
            q, nullptr, WH[t][0], WL[t][0], ib1 + t*128, WH[t][1], WL[t][1], ib2 + t*384,
            s384, nullptr, nullptr, nullptr, nullptr, nullptr, 0, NA);
        // edge message passing (owner-exclusive, MFMA filter dots)
        k_edgeM<<<NA*2, 64, 0, stream>>>(t, phi_s, df_s, j_s, rowptr, s384,
                                         mu_cur, wfh, wfl, q, mu_nxt);
        { float* tmp = mu_cur; mu_cur = mu_nxt; mu_nxt = tmp; }
        // FieldInteraction: a_v = mu@vW; then sMLP with fused field update
        k_gmm2<0><<<dim3(G64x3, 2), 256, 0, stream>>>(mu_cur, WH[t][4], WL[t][4], nullptr, s384, NA*3, 128, 128);
        k_mlp<128,128,0,1><<<G32, 256, 0, stream>>>(
            q, nullptr, WH[t][2], WL[t][2], sb1 + t*128, WH[t][3], WL[t][3], sb2 + t*128,
            nullptr, s384, Eat, nullptr, mu_cur, nullptr, 0, NA);
        // Mixing: mumix = mu@mmW; mMLP with ctx prologue + fused mixupd (+pack)
        k_gmm2<0><<<dim3(G64x3, 4), 256, 0, stream>>>(mu_cur, WH[t][5], WL[t][5], nullptr, mumix, NA*3, 128, 256);
        k_mlp<256,384,1,2><<<G32, 256, 0, stream>>>(
            q, mumix, WH[t][6], WL[t][6], mb1 + t*128, WH[t][7], WL[t][7], mb2 + t*384,
            nullptr, nullptr, nullptr, q, mu_cur, out, (t == 2) ? 1 : 0, NA);
    }
}

// Round 10
// 1016.715 us; speedup vs baseline: 1.4872x; 1.4872x over previous
//
#include <hip/hip_runtime.h>

#define NA 10000
#define NE 320000

typedef short short8 __attribute__((ext_vector_type(8)));
typedef unsigned short us4 __attribute__((ext_vector_type(4)));
typedef float f32x4 __attribute__((ext_vector_type(4)));

__device__ __forceinline__ float silu_f(float v) { return v / (1.0f + __expf(-v)); }

__device__ __forceinline__ void split_bf16(float x, unsigned short& h, unsigned short& l)
{
    unsigned int u = __float_as_uint(x);
    h = (unsigned short)(u >> 16);
    float hf = __uint_as_float((unsigned int)h << 16);
    unsigned int ul = __float_as_uint(x - hf) + 0x8000u;
    l = (unsigned short)(ul >> 16);
}

// ---------------- init ----------------------------------------------------------
__global__ __launch_bounds__(256) void k_init(
    const int* __restrict__ Z, const int* __restrict__ idx_m,
    const float* __restrict__ emb, const float* __restrict__ e_field,
    float* __restrict__ q, float* __restrict__ mu,
    float* __restrict__ Eat, int* __restrict__ counts, int* __restrict__ cursor)
{
    int gid = blockIdx.x * 256 + threadIdx.x;
    if (gid < NA * 384) mu[gid] = 0.0f;
    if (gid < NA * 128) {
        int i = gid >> 7, f = gid & 127;
        q[gid] = emb[Z[i] * 128 + f];
    }
    if (gid < NA * 3) {
        int i = gid / 3, d = gid - i * 3;
        Eat[gid] = e_field[idx_m[i] * 3 + d];
    }
    if (gid < NA) { counts[gid] = 0; cursor[gid] = 0; }
}

// ---------------- histogram idx_i -----------------------------------------------
__global__ __launch_bounds__(256) void k_count(
    const int* __restrict__ idx_i, int* __restrict__ counts)
{
    int e = blockIdx.x * 256 + threadIdx.x;
    if (e < NE) atomicAdd(&counts[idx_i[e]], 1);
}

// ---------------- exclusive scan -------------------------------------------------
__global__ __launch_bounds__(256) void k_scan(const int* __restrict__ counts,
                                              int* __restrict__ rowptr)
{
    __shared__ int part[256];
    int tid = threadIdx.x;
    const int CH = (NA + 255) / 256;
    int base = tid * CH;
    int s = 0;
    for (int i2 = 0; i2 < CH; i2++) {
        int idx = base + i2;
        if (idx < NA) s += counts[idx];
    }
    part[tid] = s;
    __syncthreads();
    for (int ofs = 1; ofs < 256; ofs <<= 1) {
        int v = part[tid];
        int add = (tid >= ofs) ? part[tid - ofs] : 0;
        __syncthreads();
        part[tid] = v + add;
        __syncthreads();
    }
    int run = (tid > 0) ? part[tid - 1] : 0;
    for (int i2 = 0; i2 < CH; i2++) {
        int idx = base + i2;
        if (idx < NA) { rowptr[idx] = run; run += counts[idx]; }
        else if (idx == NA) rowptr[NA] = run;
    }
}

// ---------------- geometry + scatter into CSR order -----------------------------
__global__ __launch_bounds__(256) void k_geom_scatter(
    const float* __restrict__ r_ij, const int* __restrict__ idx_i,
    const int* __restrict__ idx_j, const int* __restrict__ rowptr,
    int* __restrict__ cursor, float* __restrict__ phi_s,
    float4* __restrict__ df_s, int* __restrict__ j_s)
{
    int e = blockIdx.x * 256 + threadIdx.x;
    if (e >= NE) return;
    float x = r_ij[e*3+0], y = r_ij[e*3+1], z = r_ij[e*3+2];
    float d = sqrtf(x*x + y*y + z*z);
    float inv = 1.0f / d;
    float fc = (d < 5.0f) ? 0.5f * (__cosf(d * 0.628318530717958648f) + 1.0f) : 0.0f;
    int i = idx_i[e];
    int pos = rowptr[i] + atomicAdd(&cursor[i], 1);
    float4 dv; dv.x = x*inv; dv.y = y*inv; dv.z = z*inv; dv.w = fc;
    df_s[pos] = dv;
    j_s[pos] = idx_j[e];
    const float invw = 19.0f / 5.0f;
    float ph[20];
    #pragma unroll
    for (int k = 0; k < 20; k++) {
        float off = (5.0f / 19.0f) * (float)k;
        float u = (d - off) * invw;
        ph[k] = __expf(-0.5f * u * u) * fc;
    }
    #pragma unroll
    for (int c = 0; c < 5; c++) {
        float4 pv; pv.x = ph[c*4]; pv.y = ph[c*4+1]; pv.z = ph[c*4+2]; pv.w = ph[c*4+3];
        *(float4*)(phi_s + (size_t)pos*20 + c*4) = pv;
    }
}

// ---------------- weight prep: hi/lo bf16 split, MFMA-fragment-linear -----------
struct WDesc { const float* src; unsigned short* dh; unsigned short* dl; int K; int N; };
struct WPack { WDesc w[24]; };

__global__ __launch_bounds__(256) void k_wprep(WPack P)
{
    WDesc d = P.w[blockIdx.y];
    int kBlks = d.K >> 5, nStrips = d.N >> 4;
    int total = nStrips * kBlks * 64;
    int g = blockIdx.x * 256 + threadIdx.x;
    if (g >= total) return;
    int lane = g & 63, rem = g >> 6;
    int kb = rem % kBlks, sIdx = rem / kBlks;
    int m16 = lane & 15, quad = lane >> 4;
    int n = sIdx * 16 + m16;
    int kbase = kb * 32 + quad * 8;
    size_t dofs = (size_t)g * 8;
    #pragma unroll
    for (int jj = 0; jj < 8; jj++) {
        unsigned short h, l;
        split_bf16(d.src[(size_t)(kbase + jj) * d.N + n], h, l);
        d.dh[dofs + jj] = h;
        d.dl[dofs + jj] = l;
    }
}

// ---------------- filter weight prep: W(20) + bias(k=20), pad K=32 --------------
__global__ __launch_bounds__(256) void k_wfprep(
    const float* __restrict__ filt_W, const float* __restrict__ filt_b,
    unsigned short* __restrict__ wfh, unsigned short* __restrict__ wfl)
{
    int g = blockIdx.x * 256 + threadIdx.x;
    if (g >= 3 * 24 * 64) return;
    int lane = g & 63, rem = g >> 6;
    int st = rem % 24, t = rem / 24;
    int col = lane & 15, quad = lane >> 4;
    int tcol = t * 384 + st * 16 + col;
    size_t dofs = (size_t)g * 8;
    #pragma unroll
    for (int j = 0; j < 8; j++) {
        int k = quad * 8 + j;
        float v = 0.0f;
        if (k < 20) v = filt_W[k * 1152 + tcol];
        else if (k == 20) v = filt_b[tcol];
        unsigned short hh, ll;
        split_bf16(v, hh, ll);
        wfh[dofs + j] = hh;
        wfl[dofs + j] = ll;
    }
}

// ---------------- MFMA GEMM (bf16 split-3), 64x64 tile --------------------------
template<int ACT>
__global__ __launch_bounds__(256) void k_gmm2(
    const float* __restrict__ A,
    const unsigned short* __restrict__ Bh, const unsigned short* __restrict__ Bl,
    const float* __restrict__ bias, float* __restrict__ C,
    int M, int K, int N)
{
    __shared__ unsigned short Ahs[64 * 40];
    __shared__ unsigned short Als[64 * 40];
    int tid = threadIdx.x, lane = tid & 63, wv = tid >> 6;
    int i0 = blockIdx.x * 64, n0 = blockIdx.y * 64;
    int m16 = lane & 15, quad = lane >> 4;
    int kBlks = K >> 5;
    int sIdx = blockIdx.y * 4 + wv;

    f32x4 acc[4];
    #pragma unroll
    for (int a = 0; a < 4; a++) acc[a] = 0.0f;

    for (int kb = 0; kb < kBlks; kb++) {
        int k0 = kb << 5;
        __syncthreads();
        #pragma unroll
        for (int s = 0; s < 2; s++) {
            int idx = s * 256 + tid;
            int r = idx >> 3, c4 = (idx & 7) << 2;
            float4 v = {0.f, 0.f, 0.f, 0.f};
            if (i0 + r < M) v = *(const float4*)(A + (size_t)(i0 + r) * K + k0 + c4);
            unsigned short h0,l0,h1,l1,h2,l2,h3,l3;
            split_bf16(v.x, h0, l0); split_bf16(v.y, h1, l1);
            split_bf16(v.z, h2, l2); split_bf16(v.w, h3, l3);
            us4 hv = {h0, h1, h2, h3}, lv = {l0, l1, l2, l3};
            *(us4*)(Ahs + r * 40 + c4) = hv;
            *(us4*)(Als + r * 40 + c4) = lv;
        }
        __syncthreads();
        size_t bofs = (((size_t)sIdx * kBlks + kb) * 64 + lane) * 8;
        short8 bh = *(const short8*)(Bh + bofs);
        short8 bl = *(const short8*)(Bl + bofs);
        #pragma unroll
        for (int tm = 0; tm < 4; tm++) {
            short8 ah = *(const short8*)(Ahs + (tm * 16 + m16) * 40 + quad * 8);
            short8 al = *(const short8*)(Als + (tm * 16 + m16) * 40 + quad * 8);
            acc[tm] = __builtin_amdgcn_mfma_f32_16x16x32_bf16(ah, bh, acc[tm], 0, 0, 0);
            acc[tm] = __builtin_amdgcn_mfma_f32_16x16x32_bf16(ah, bl, acc[tm], 0, 0, 0);
            acc[tm] = __builtin_amdgcn_mfma_f32_16x16x32_bf16(al, bh, acc[tm], 0, 0, 0);
        }
    }
    int col = n0 + wv * 16 + m16;
    float bv = bias ? bias[col] : 0.0f;
    #pragma unroll
    for (int tm = 0; tm < 4; tm++) {
        #pragma unroll
        for (int r = 0; r < 4; r++) {
            int row = i0 + tm * 16 + quad * 4 + r;
            if (row < M) {
                float v = acc[tm][r] + bv;
                if (ACT) v = silu_f(v);
                C[(size_t)row * N + col] = v;
            }
        }
    }
}

// ---------------- fused MLP with prologue/epilogue variants ----------------------
template<int K1, int N2, int PRO, int EPI>
__global__ __launch_bounds__(256, 2) void k_mlp(
    const float* __restrict__ A, const float* __restrict__ mumix,
    const unsigned short* __restrict__ B1h, const unsigned short* __restrict__ B1l,
    const float* __restrict__ b1,
    const unsigned short* __restrict__ B2h, const unsigned short* __restrict__ B2l,
    const float* __restrict__ b2,
    float* __restrict__ C,
    const float* __restrict__ av, const float* __restrict__ Eat,
    float* __restrict__ qRW, float* __restrict__ muRW,
    float* __restrict__ outPk, int last, int M)
{
    const int KB1 = K1 / 32;
    const int S2  = N2 / 64;
    __shared__ unsigned short A1h[32 * 40];
    __shared__ unsigned short A1l[32 * 40];
    __shared__ unsigned short Hh[32 * 136];
    __shared__ unsigned short Hl[32 * 136];
    __shared__ float Ys[EPI == 2 ? 32 * 384 : 1];

    int tid = threadIdx.x, lane = tid & 63, wv = tid >> 6;
    int i0 = blockIdx.x * 32;
    int m16 = lane & 15, quad = lane >> 4;

    f32x4 acc1[2][2];
    #pragma unroll
    for (int s = 0; s < 2; s++)
        #pragma unroll
        for (int tm = 0; tm < 2; tm++) acc1[s][tm] = 0.0f;

    for (int kb = 0; kb < KB1; kb++) {
        int k0 = kb << 5;
        __syncthreads();
        {
            int r = tid >> 3, c4 = (tid & 7) << 2;
            int row = i0 + r;
            float4 v = {0.f, 0.f, 0.f, 0.f};
            if (row < M) {
                if (PRO == 0) {
                    v = *(const float4*)(A + (size_t)row * K1 + k0 + c4);
                } else {
                    int g = k0 + c4;
                    if (g < 128) {
                        v = *(const float4*)(A + (size_t)row * 128 + g);
                    } else {
                        int f = g - 128;
                        float4 v0 = *(const float4*)(mumix + ((size_t)row*3 + 0)*256 + f);
                        float4 v1 = *(const float4*)(mumix + ((size_t)row*3 + 1)*256 + f);
                        float4 v2 = *(const float4*)(mumix + ((size_t)row*3 + 2)*256 + f);
                        v.x = sqrtf(v0.x*v0.x + v1.x*v1.x + v2.x*v2.x + 1e-8f);
                        v.y = sqrtf(v0.y*v0.y + v1.y*v1.y + v2.y*v2.y + 1e-8f);
                        v.z = sqrtf(v0.z*v0.z + v1.z*v1.z + v2.z*v2.z + 1e-8f);
                        v.w = sqrtf(v0.w*v0.w + v1.w*v1.w + v2.w*v2.w + 1e-8f);
                    }
                }
            }
            unsigned short h0,l0,h1,l1,h2,l2,h3,l3;
            split_bf16(v.x, h0, l0); split_bf16(v.y, h1, l1);
            split_bf16(v.z, h2, l2); split_bf16(v.w, h3, l3);
            us4 hv = {h0, h1, h2, h3}, lv = {l0, l1, l2, l3};
            *(us4*)(A1h + r * 40 + c4) = hv;
            *(us4*)(A1l + r * 40 + c4) = lv;
        }
        __syncthreads();
        #pragma unroll
        for (int tm = 0; tm < 2; tm++) {
            short8 ah = *(const short8*)(A1h + (tm * 16 + m16) * 40 + quad * 8);
            short8 al = *(const short8*)(A1l + (tm * 16 + m16) * 40 + quad * 8);
            #pragma unroll
            for (int s = 0; s < 2; s++) {
                int sIdx = wv * 2 + s;
                size_t bofs = (((size_t)sIdx * KB1 + kb) * 64 + lane) * 8;
                short8 bh = *(const short8*)(B1h + bofs);
                short8 bl = *(const short8*)(B1l + bofs);
                acc1[s][tm] = __builtin_amdgcn_mfma_f32_16x16x32_bf16(ah, bh, acc1[s][tm], 0, 0, 0);
                acc1[s][tm] = __builtin_amdgcn_mfma_f32_16x16x32_bf16(ah, bl, acc1[s][tm], 0, 0, 0);
                acc1[s][tm] = __builtin_amdgcn_mfma_f32_16x16x32_bf16(al, bh, acc1[s][tm], 0, 0, 0);
            }
        }
    }
    __syncthreads();
    #pragma unroll
    for (int s = 0; s < 2; s++) {
        int col = wv * 32 + s * 16 + m16;
        float bb = b1[col];
        #pragma unroll
        for (int tm = 0; tm < 2; tm++) {
            #pragma unroll
            for (int r = 0; r < 4; r++) {
                int row = tm * 16 + quad * 4 + r;
                float v = silu_f(acc1[s][tm][r] + bb);
                unsigned short h, l;
                split_bf16(v, h, l);
                Hh[row * 136 + col] = h;
                Hl[row * 136 + col] = l;
            }
        }
    }
    __syncthreads();

    f32x4 acc2[S2][2];
    #pragma unroll
    for (int s = 0; s < S2; s++)
        #pragma unroll
        for (int tm = 0; tm < 2; tm++) acc2[s][tm] = 0.0f;

    #pragma unroll
    for (int kb = 0; kb < 4; kb++) {
        short8 ah[2], al[2];
        #pragma unroll
        for (int tm = 0; tm < 2; tm++) {
            ah[tm] = *(const short8*)(Hh + (tm * 16 + m16) * 136 + kb * 32 + quad * 8);
            al[tm] = *(const short8*)(Hl + (tm * 16 + m16) * 136 + kb * 32 + quad * 8);
        }
        #pragma unroll
        for (int s = 0; s < S2; s++) {
            int sIdx = wv * S2 + s;
            size_t bofs = (((size_t)sIdx * 4 + kb) * 64 + lane) * 8;
            short8 bh = *(const short8*)(B2h + bofs);
            short8 bl = *(const short8*)(B2l + bofs);
            #pragma unroll
            for (int tm = 0; tm < 2; tm++) {
                acc2[s][tm] = __builtin_amdgcn_mfma_f32_16x16x32_bf16(ah[tm], bh, acc2[s][tm], 0, 0, 0);
                acc2[s][tm] = __builtin_amdgcn_mfma_f32_16x16x32_bf16(ah[tm], bl, acc2[s][tm], 0, 0, 0);
                acc2[s][tm] = __builtin_amdgcn_mfma_f32_16x16x32_bf16(al[tm], bh, acc2[s][tm], 0, 0, 0);
            }
        }
    }

    if (EPI == 0) {
        #pragma unroll
        for (int s = 0; s < S2; s++) {
            int col = (wv * S2 + s) * 16 + m16;
            float bb = b2 ? b2[col] : 0.0f;
            #pragma unroll
            for (int tm = 0; tm < 2; tm++) {
                #pragma unroll
                for (int r = 0; r < 4; r++) {
                    int row = i0 + tm * 16 + quad * 4 + r;
                    if (row < M) C[(size_t)row * N2 + col] = acc2[s][tm][r] + bb;
                }
            }
        }
    } else if (EPI == 1) {
        #pragma unroll
        for (int s = 0; s < S2; s++) {
            int col = (wv * S2 + s) * 16 + m16;
            float bb = b2[col];
            #pragma unroll
            for (int tm = 0; tm < 2; tm++) {
                #pragma unroll
                for (int r = 0; r < 4; r++) {
                    int row = i0 + tm * 16 + quad * 4 + r;
                    if (row < M) {
                        float as = acc2[s][tm][r] + bb;
                        float E0 = Eat[row*3+0], E1 = Eat[row*3+1], E2 = Eat[row*3+2];
                        size_t b0 = ((size_t)row*3 + 0)*128 + col;
                        size_t b1o = ((size_t)row*3 + 1)*128 + col;
                        size_t b2o = ((size_t)row*3 + 2)*128 + col;
                        float a0 = av[b0], a1 = av[b1o], a2 = av[b2o];
                        float dot = a0*E0 + a1*E1 + a2*E2;
                        muRW[b0] += as*E0 - dot*a0;
                        muRW[b1o] += as*E1 - dot*a1;
                        muRW[b2o] += as*E2 - dot*a2;
                    }
                }
            }
        }
    } else {
        #pragma unroll
        for (int s = 0; s < S2; s++) {
            int col = (wv * S2 + s) * 16 + m16;
            float bb = b2[col];
            #pragma unroll
            for (int tm = 0; tm < 2; tm++) {
                #pragma unroll
                for (int r = 0; r < 4; r++) {
                    int row = tm * 16 + quad * 4 + r;
                    Ys[row * 384 + col] = acc2[s][tm][r] + bb;
                }
            }
        }
        __syncthreads();
        int f = tid & 127;
        #pragma unroll
        for (int it = 0; it < 16; it++) {
            int row = (tid >> 7) + it * 2;
            int i = i0 + row;
            if (i < M) {
                float yq  = Ys[row * 384 + f];
                float ym  = Ys[row * 384 + 128 + f];
                float yqm = Ys[row * 384 + 256 + f];
                float sdot = 0.0f;
                float W[3];
                #pragma unroll
                for (int d = 0; d < 3; d++) {
                    float Vd = mumix[((size_t)i*3 + d)*256 + f];
                    W[d]     = mumix[((size_t)i*3 + d)*256 + 128 + f];
                    sdot += Vd * W[d];
                }
                float qn = qRW[(size_t)i*128 + f] + yq + yqm * sdot;
                qRW[(size_t)i*128 + f] = qn;
                float mun[3];
                #pragma unroll
                for (int d = 0; d < 3; d++) {
                    size_t mo = ((size_t)i*3 + d)*128 + f;
                    mun[d] = muRW[mo] + ym * W[d];
                    muRW[mo] = mun[d];
                }
                if (last) {
                    outPk[(size_t)i*512 + f] = qn;
                    #pragma unroll
                    for (int d = 0; d < 3; d++)
                        outPk[(size_t)i*512 + 128 + d*128 + f] = mun[d];
                }
            }
        }
    }
}

// ---------------- edge aggregation: MFMA filter dots, 4 waves/block -------------
// Wave g = blockIdx.x*4 + (tid>>6) handles (atom ia = g>>1, half h = g&1).
// Identical math to R9's k_edgeM; 256-thread blocks lift the workgroup-slot
// occupancy cap (R9: 64-thr blocks -> 21% occupancy). No barriers, no LDS.
__global__ __launch_bounds__(256) void k_edgeM(
    int t, const float* __restrict__ phi_s, const float4* __restrict__ df_s,
    const int* __restrict__ j_s, const int* __restrict__ rowptr,
    const float* __restrict__ x, const float* __restrict__ mu_in,
    const unsigned short* __restrict__ wfh, const unsigned short* __restrict__ wfl,
    float* __restrict__ q, float* __restrict__ mu_out)
{
    int lane = threadIdx.x & 63;
    int g  = blockIdx.x * 4 + (threadIdx.x >> 6);
    int ia = g >> 1;
    int h  = g & 1;
    int col = lane & 15, quad = lane >> 4;

    int p0 = rowptr[ia], p1 = rowptr[ia + 1];

    float accq[4] = {};
    float accd[3][4] = {};

    for (int pb = p0; pb < p1; pb += 16) {
        // ---- A fragment: 16 edges x K32 (phi*fc at k<20, fc at k=20) ----
        int e = pb + col;
        bool val = (e < p1);
        int ec = val ? e : (p1 - 1);
        float av[8] = {0,0,0,0,0,0,0,0};
        if (val) {
            const float* pr = phi_s + (size_t)ec * 20;
            if (quad == 0) {
                float4 a = *(const float4*)(pr);
                float4 b = *(const float4*)(pr + 4);
                av[0]=a.x; av[1]=a.y; av[2]=a.z; av[3]=a.w;
                av[4]=b.x; av[5]=b.y; av[6]=b.z; av[7]=b.w;
            } else if (quad == 1) {
                float4 a = *(const float4*)(pr + 8);
                float4 b = *(const float4*)(pr + 12);
                av[0]=a.x; av[1]=a.y; av[2]=a.z; av[3]=a.w;
                av[4]=b.x; av[5]=b.y; av[6]=b.z; av[7]=b.w;
            } else if (quad == 2) {
                float4 a = *(const float4*)(pr + 16);
                av[0]=a.x; av[1]=a.y; av[2]=a.z; av[3]=a.w;
                av[4]=df_s[ec].w;               // k=20 -> fcut (bias row)
            }
            // quad 3: all zero (k=24..31 pad)
        }
        short8 ah, al;
        #pragma unroll
        for (int j = 0; j < 8; j++) {
            unsigned short hh, ll;
            split_bf16(av[j], hh, ll);
            ah[j] = (short)hh; al[j] = (short)ll;
        }

        // ---- filter dots via MFMA: 3 channels x 4 strips ----
        f32x4 dt[3][4];
        #pragma unroll
        for (int c = 0; c < 3; c++) {
            #pragma unroll
            for (int s = 0; s < 4; s++) {
                int st = c * 8 + h * 4 + s;
                size_t bo = (((size_t)(t * 24 + st)) * 64 + lane) * 8;
                short8 bh = *(const short8*)(wfh + bo);
                short8 bl = *(const short8*)(wfl + bo);
                f32x4 d = {0.f, 0.f, 0.f, 0.f};
                d = __builtin_amdgcn_mfma_f32_16x16x32_bf16(ah, bh, d, 0, 0, 0);
                d = __builtin_amdgcn_mfma_f32_16x16x32_bf16(ah, bl, d, 0, 0, 0);
                d = __builtin_amdgcn_mfma_f32_16x16x32_bf16(al, bh, d, 0, 0, 0);
                dt[c][s] = d;
            }
        }

        // ---- gather + accumulate: lane owns edges pb + quad*4 + r ----
        #pragma unroll
        for (int r = 0; r < 4; r++) {
            int pe = pb + quad * 4 + r;
            if (pe > p1 - 1) pe = p1 - 1;     // padded rows have dt==0
            int j = j_s[pe];
            float4 dfr = df_s[pe];
            size_t xb = (size_t)j * 384 + h * 64 + col;
            size_t mb = (size_t)j * 384 + h * 64 + col;
            #pragma unroll
            for (int s = 0; s < 4; s++) {
                int o = s * 16;
                float xq  = x[xb + o];
                float xr_ = x[xb + 128 + o];
                float xm  = x[xb + 256 + o];
                float m0  = mu_in[mb + o];
                float m1  = mu_in[mb + 128 + o];
                float m2  = mu_in[mb + 256 + o];
                accq[s]    += dt[0][s][r] * xq;
                float xxr = dt[1][s][r] * xr_;
                float xxm = dt[2][s][r] * xm;
                accd[0][s] += xxr * dfr.x + xxm * m0;
                accd[1][s] += xxr * dfr.y + xxm * m1;
                accd[2][s] += xxr * dfr.z + xxm * m2;
            }
        }
    }

    // ---- cross-quad reduction ----
    #pragma unroll
    for (int s = 0; s < 4; s++) {
        accq[s] += __shfl_xor(accq[s], 16);
        accq[s] += __shfl_xor(accq[s], 32);
        #pragma unroll
        for (int d = 0; d < 3; d++) {
            accd[d][s] += __shfl_xor(accd[d][s], 16);
            accd[d][s] += __shfl_xor(accd[d][s], 32);
        }
    }
    if (quad == 0) {
        #pragma unroll
        for (int s = 0; s < 4; s++) {
            size_t qo = (size_t)ia * 128 + h * 64 + s * 16 + col;
            q[qo] += accq[s];
            #pragma unroll
            for (int d = 0; d < 3; d++) {
                size_t mo = ((size_t)ia * 3 + d) * 128 + h * 64 + s * 16 + col;
                mu_out[mo] = mu_in[mo] + accd[d][s];
            }
        }
    }
}

extern "C" void kernel_launch(void* const* d_in, const int* in_sizes, int n_in,
                              void* d_out, int out_size, void* d_ws, size_t ws_size,
                              hipStream_t stream)
{
    const int*   Z       = (const int*)d_in[0];
    const float* r_ij    = (const float*)d_in[1];
    const int*   idx_i   = (const int*)d_in[2];
    const int*   idx_j   = (const int*)d_in[3];
    const int*   idx_m   = (const int*)d_in[4];
    const float* e_field = (const float*)d_in[5];
    const float* emb     = (const float*)d_in[6];
    const float* filt_W  = (const float*)d_in[7];
    const float* filt_b  = (const float*)d_in[8];
    const float* iW1     = (const float*)d_in[9];
    const float* ib1     = (const float*)d_in[10];
    const float* iW2     = (const float*)d_in[11];
    const float* ib2     = (const float*)d_in[12];
    const float* sW1     = (const float*)d_in[13];
    const float* sb1     = (const float*)d_in[14];
    const float* sW2     = (const float*)d_in[15];
    const float* sb2     = (const float*)d_in[16];
    const float* vW      = (const float*)d_in[17];
    const float* mmW     = (const float*)d_in[18];
    const float* mW1     = (const float*)d_in[19];
    const float* mb1     = (const float*)d_in[20];
    const float* mW2     = (const float*)d_in[21];
    const float* mb2     = (const float*)d_in[22];
    float* out = (float*)d_out;

    float* base = (float*)d_ws;
    size_t off = 0;
    auto alloc = [&](size_t n) { float* p = base + off; off += (n + 255) & ~(size_t)255; return p; };
    float* q     = alloc((size_t)NA*128);
    float* mu_a  = alloc((size_t)NA*384);
    float* mu_b  = alloc((size_t)NA*384);
    float* s384  = alloc((size_t)NA*384);   // x, then a_v
    float* mumix = alloc((size_t)NA*768);
    float* Eat   = alloc((size_t)NA*3);
    float* phi_s = alloc((size_t)NE*20);
    float4* df_s = (float4*)alloc((size_t)NE*4);
    int* rowptr  = (int*)alloc(NA + 1);
    int* counts  = (int*)alloc(NA);
    int* cursor  = (int*)alloc(NA);
    int* j_s     = (int*)alloc(NE);
    unsigned short* wth = (unsigned short*)alloc(344064 + 256);
    unsigned short* wtl = (unsigned short*)alloc(344064 + 256);
    unsigned short* wfh = (unsigned short*)alloc(3*24*64*8/2 + 256);
    unsigned short* wfl = (unsigned short*)alloc(3*24*64*8/2 + 256);
    (void)ws_size; (void)in_sizes; (void)n_in; (void)out_size;

    WPack P;
    size_t woff = 0;
    unsigned short* WH[3][8];
    unsigned short* WL[3][8];
    int nw = 0;
    auto reg = [&](const float* src, int K, int N, int t, int slot) {
        P.w[nw].src = src; P.w[nw].dh = wth + woff; P.w[nw].dl = wtl + woff;
        P.w[nw].K = K; P.w[nw].N = N;
        WH[t][slot] = wth + woff; WL[t][slot] = wtl + woff;
        woff += (size_t)K * N; nw++;
    };
    for (int t = 0; t < 3; t++) {
        reg(iW1 + t*128*128, 128, 128, t, 0);
        reg(iW2 + t*128*384, 128, 384, t, 1);
        reg(sW1 + t*128*128, 128, 128, t, 2);
        reg(sW2 + t*128*128, 128, 128, t, 3);
        reg(vW  + t*128*128, 128, 128, t, 4);
        reg(mmW + t*128*256, 128, 256, t, 5);
        reg(mW1 + t*256*128, 256, 128, t, 6);
        reg(mW2 + t*128*384, 128, 384, t, 7);
    }

    k_wprep       <<<dim3(24, 24),          256, 0, stream>>>(P);
    k_wfprep      <<<18,                    256, 0, stream>>>(filt_W, filt_b, wfh, wfl);
    k_init        <<<(NA*384 + 255)/256,    256, 0, stream>>>(Z, idx_m, emb, e_field, q, mu_a, Eat, counts, cursor);
    k_count       <<<(NE + 255)/256,        256, 0, stream>>>(idx_i, counts);
    k_scan        <<<1,                     256, 0, stream>>>(counts, rowptr);
    k_geom_scatter<<<(NE + 255)/256,        256, 0, stream>>>(r_ij, idx_i, idx_j, rowptr, cursor,
                                                              phi_s, df_s, j_s);

    const int G32   = (NA + 31) / 32;       // 313
    const int G64x3 = (NA*3 + 63) / 64;     // 469
    float* mu_cur = mu_a;
    float* mu_nxt = mu_b;
    for (int t = 0; t < 3; t++) {
        // Interaction MLP: x = silu(q@iW1+b1)@iW2+b2
        k_mlp<128,384,0,0><<<G32, 256, 0, stream>>>(
            q, nullptr, WH[t][0], WL[t][0], ib1 + t*128, WH[t][1], WL[t][1], ib2 + t*384,
            s384, nullptr, nullptr, nullptr, nullptr, nullptr, 0, NA);
        // edge message passing (owner-exclusive, MFMA filter dots, 4 waves/block)
        k_edgeM<<<NA/2, 256, 0, stream>>>(t, phi_s, df_s, j_s, rowptr, s384,
                                          mu_cur, wfh, wfl, q, mu_nxt);
        { float* tmp = mu_cur; mu_cur = mu_nxt; mu_nxt = tmp; }
        // FieldInteraction: a_v = mu@vW; then sMLP with fused field update
        k_gmm2<0><<<dim3(G64x3, 2), 256, 0, stream>>>(mu_cur, WH[t][4], WL[t][4], nullptr, s384, NA*3, 128, 128);
        k_mlp<128,128,0,1><<<G32, 256, 0, stream>>>(
            q, nullptr, WH[t][2], WL[t][2], sb1 + t*128, WH[t][3], WL[t][3], sb2 + t*128,
            nullptr, s384, Eat, nullptr, mu_cur, nullptr, 0, NA);
        // Mixing: mumix = mu@mmW; mMLP with ctx prologue + fused mixupd (+pack)
        k_gmm2<0><<<dim3(G64x3, 4), 256, 0, stream>>>(mu_cur, WH[t][5], WL[t][5], nullptr, mumix, NA*3, 128, 256);
        k_mlp<256,384,1,2><<<G32, 256, 0, stream>>>(
            q, mumix, WH[t][6], WL[t][6], mb1 + t*128, WH[t][7], WL[t][7], mb2 + t*384,
            nullptr, nullptr, nullptr, q, mu_cur, out, (t == 2) ? 1 : 0, NA);
    }
}

// Round 12
// 1006.810 us; speedup vs baseline: 1.5019x; 1.0098x over previous
//
#include <hip/hip_runtime.h>

#define NA 10000
#define NE 320000

typedef short short8 __attribute__((ext_vector_type(8)));
typedef unsigned short us4 __attribute__((ext_vector_type(4)));
typedef float f32x4 __attribute__((ext_vector_type(4)));

__device__ __forceinline__ float silu_f(float v) { return v / (1.0f + __expf(-v)); }

__device__ __forceinline__ void split_bf16(float x, unsigned short& h, unsigned short& l)
{
    unsigned int u = __float_as_uint(x);
    h = (unsigned short)(u >> 16);
    float hf = __uint_as_float((unsigned int)h << 16);
    unsigned int ul = __float_as_uint(x - hf) + 0x8000u;
    l = (unsigned short)(ul >> 16);
}

// ---------------- init ----------------------------------------------------------
__global__ __launch_bounds__(256) void k_init(
    const int* __restrict__ Z, const int* __restrict__ idx_m,
    const float* __restrict__ emb, const float* __restrict__ e_field,
    float* __restrict__ q, float* __restrict__ mu,
    float* __restrict__ Eat, int* __restrict__ counts, int* __restrict__ cursor)
{
    int gid = blockIdx.x * 256 + threadIdx.x;
    if (gid < NA * 384) mu[gid] = 0.0f;
    if (gid < NA * 128) {
        int i = gid >> 7, f = gid & 127;
        q[gid] = emb[Z[i] * 128 + f];
    }
    if (gid < NA * 3) {
        int i = gid / 3, d = gid - i * 3;
        Eat[gid] = e_field[idx_m[i] * 3 + d];
    }
    if (gid < NA) { counts[gid] = 0; cursor[gid] = 0; }
}

// ---------------- histogram idx_i -----------------------------------------------
__global__ __launch_bounds__(256) void k_count(
    const int* __restrict__ idx_i, int* __restrict__ counts)
{
    int e = blockIdx.x * 256 + threadIdx.x;
    if (e < NE) atomicAdd(&counts[idx_i[e]], 1);
}

// ---------------- exclusive scan -------------------------------------------------
__global__ __launch_bounds__(256) void k_scan(const int* __restrict__ counts,
                                              int* __restrict__ rowptr)
{
    __shared__ int part[256];
    int tid = threadIdx.x;
    const int CH = (NA + 255) / 256;
    int base = tid * CH;
    int s = 0;
    for (int i2 = 0; i2 < CH; i2++) {
        int idx = base + i2;
        if (idx < NA) s += counts[idx];
    }
    part[tid] = s;
    __syncthreads();
    for (int ofs = 1; ofs < 256; ofs <<= 1) {
        int v = part[tid];
        int add = (tid >= ofs) ? part[tid - ofs] : 0;
        __syncthreads();
        part[tid] = v + add;
        __syncthreads();
    }
    int run = (tid > 0) ? part[tid - 1] : 0;
    for (int i2 = 0; i2 < CH; i2++) {
        int idx = base + i2;
        if (idx < NA) { rowptr[idx] = run; run += counts[idx]; }
        else if (idx == NA) rowptr[NA] = run;
    }
}

// ---------------- geometry + scatter into CSR order -----------------------------
__global__ __launch_bounds__(256) void k_geom_scatter(
    const float* __restrict__ r_ij, const int* __restrict__ idx_i,
    const int* __restrict__ idx_j, const int* __restrict__ rowptr,
    int* __restrict__ cursor, float* __restrict__ phi_s,
    float4* __restrict__ df_s, int* __restrict__ j_s)
{
    int e = blockIdx.x * 256 + threadIdx.x;
    if (e >= NE) return;
    float x = r_ij[e*3+0], y = r_ij[e*3+1], z = r_ij[e*3+2];
    float d = sqrtf(x*x + y*y + z*z);
    float inv = 1.0f / d;
    float fc = (d < 5.0f) ? 0.5f * (__cosf(d * 0.628318530717958648f) + 1.0f) : 0.0f;
    int i = idx_i[e];
    int pos = rowptr[i] + atomicAdd(&cursor[i], 1);
    float4 dv; dv.x = x*inv; dv.y = y*inv; dv.z = z*inv; dv.w = fc;
    df_s[pos] = dv;
    j_s[pos] = idx_j[e];
    const float invw = 19.0f / 5.0f;
    float ph[20];
    #pragma unroll
    for (int k = 0; k < 20; k++) {
        float off = (5.0f / 19.0f) * (float)k;
        float u = (d - off) * invw;
        ph[k] = __expf(-0.5f * u * u) * fc;
    }
    #pragma unroll
    for (int c = 0; c < 5; c++) {
        float4 pv; pv.x = ph[c*4]; pv.y = ph[c*4+1]; pv.z = ph[c*4+2]; pv.w = ph[c*4+3];
        *(float4*)(phi_s + (size_t)pos*20 + c*4) = pv;
    }
}

// ---------------- weight prep: hi/lo bf16 split, MFMA-fragment-linear -----------
struct WDesc { const float* src; unsigned short* dh; unsigned short* dl; int K; int N; };
struct WPack { WDesc w[24]; };

__global__ __launch_bounds__(256) void k_wprep(WPack P)
{
    WDesc d = P.w[blockIdx.y];
    int kBlks = d.K >> 5, nStrips = d.N >> 4;
    int total = nStrips * kBlks * 64;
    int g = blockIdx.x * 256 + threadIdx.x;
    if (g >= total) return;
    int lane = g & 63, rem = g >> 6;
    int kb = rem % kBlks, sIdx = rem / kBlks;
    int m16 = lane & 15, quad = lane >> 4;
    int n = sIdx * 16 + m16;
    int kbase = kb * 32 + quad * 8;
    size_t dofs = (size_t)g * 8;
    #pragma unroll
    for (int jj = 0; jj < 8; jj++) {
        unsigned short h, l;
        split_bf16(d.src[(size_t)(kbase + jj) * d.N + n], h, l);
        d.dh[dofs + jj] = h;
        d.dl[dofs + jj] = l;
    }
}

// ---------------- filter weight prep: W(20) + bias(k=20), pad K=32 --------------
__global__ __launch_bounds__(256) void k_wfprep(
    const float* __restrict__ filt_W, const float* __restrict__ filt_b,
    unsigned short* __restrict__ wfh, unsigned short* __restrict__ wfl)
{
    int g = blockIdx.x * 256 + threadIdx.x;
    if (g >= 3 * 24 * 64) return;
    int lane = g & 63, rem = g >> 6;
    int st = rem % 24, t = rem / 24;
    int col = lane & 15, quad = lane >> 4;
    int tcol = t * 384 + st * 16 + col;
    size_t dofs = (size_t)g * 8;
    #pragma unroll
    for (int j = 0; j < 8; j++) {
        int k = quad * 8 + j;
        float v = 0.0f;
        if (k < 20) v = filt_W[k * 1152 + tcol];
        else if (k == 20) v = filt_b[tcol];
        unsigned short hh, ll;
        split_bf16(v, hh, ll);
        wfh[dofs + j] = hh;
        wfl[dofs + j] = ll;
    }
}

// ---------------- fused MLP with pre-GEMM / prologue / epilogue variants ---------
// PRE: 0 = none; 1 = compute Gout[96 rows x 128] = mu@Bg (vW) for this block's
//      rows; 2 = Gout[96 x 256] = mu@Bg (mmW). Written to global, re-read L2-hot
//      by the prologue/epilogue below (rows are block-exclusive).
// PRO: 0 = A is [M,K1] dense; 1 = ctx mode (K1=256): cols 0..127 from q,
//      cols 128..255 = ||mu_V|| from mumix.
// EPI: 0 = write C = h2 + b2
//      1 = field: a_s consumed in-place -> mu += a_s*E - (a_v.E)a_v
//      2 = mixupd: y staged in LDS; q += yq + yqm*sdot; mu += ym*mu_W;
//          if last, also write packed out [N,4,128].
template<int K1, int N2, int PRO, int EPI, int PRE>
__global__ __launch_bounds__(256, 2) void k_mlp(
    const float* __restrict__ A, const float* __restrict__ mumix,
    const unsigned short* __restrict__ B1h, const unsigned short* __restrict__ B1l,
    const float* __restrict__ b1,
    const unsigned short* __restrict__ B2h, const unsigned short* __restrict__ B2l,
    const float* __restrict__ b2,
    const unsigned short* __restrict__ Bgh, const unsigned short* __restrict__ Bgl,
    float* __restrict__ Gout,
    float* __restrict__ C,
    const float* __restrict__ av, const float* __restrict__ Eat,
    float* __restrict__ qRW, float* __restrict__ muRW,
    float* __restrict__ outPk, int last, int M)
{
    const int KB1 = K1 / 32;
    const int S2  = N2 / 64;
    __shared__ unsigned short A1h[32 * 40];
    __shared__ unsigned short A1l[32 * 40];
    __shared__ unsigned short Hh[32 * 136];
    __shared__ unsigned short Hl[32 * 136];
    __shared__ float Ys[EPI == 2 ? 32 * 384 : 1];

    int tid = threadIdx.x, lane = tid & 63, wv = tid >> 6;
    int i0 = blockIdx.x * 32;
    int m16 = lane & 15, quad = lane >> 4;

    // ---- PRE: per-block GEMM Gout = mu @ Bg for this block's 96 mu-rows ----
    if (PRE > 0) {
        const int NG  = (PRE == 1) ? 128 : 256;
        const int SPW = NG / 64;                 // strips per wave: 2 or 4
        #pragma unroll
        for (int mt = 0; mt < 6; mt++) {
            int rowbase = i0 * 3 + mt * 16;
            f32x4 ga[SPW];
            #pragma unroll
            for (int s = 0; s < SPW; s++) ga[s] = 0.0f;
            #pragma unroll
            for (int kb = 0; kb < 4; kb++) {
                int arow = rowbase + m16;
                float va[8] = {0,0,0,0,0,0,0,0};
                if (arow < 3 * M) {
                    const float* ap = muRW + (size_t)arow * 128 + kb * 32 + quad * 8;
                    float4 u0 = *(const float4*)(ap);
                    float4 u1 = *(const float4*)(ap + 4);
                    va[0]=u0.x; va[1]=u0.y; va[2]=u0.z; va[3]=u0.w;
                    va[4]=u1.x; va[5]=u1.y; va[6]=u1.z; va[7]=u1.w;
                }
                short8 ah, al;
                #pragma unroll
                for (int j = 0; j < 8; j++) {
                    unsigned short hh, ll;
                    split_bf16(va[j], hh, ll);
                    ah[j] = (short)hh; al[j] = (short)ll;
                }
                #pragma unroll
                for (int s = 0; s < SPW; s++) {
                    int sIdx = wv * SPW + s;
                    size_t bo = (((size_t)sIdx * 4 + kb) * 64 + lane) * 8;
                    short8 bh = *(const short8*)(Bgh + bo);
                    short8 bl = *(const short8*)(Bgl + bo);
                    ga[s] = __builtin_amdgcn_mfma_f32_16x16x32_bf16(ah, bh, ga[s], 0, 0, 0);
                    ga[s] = __builtin_amdgcn_mfma_f32_16x16x32_bf16(ah, bl, ga[s], 0, 0, 0);
                    ga[s] = __builtin_amdgcn_mfma_f32_16x16x32_bf16(al, bh, ga[s], 0, 0, 0);
                }
            }
            #pragma unroll
            for (int s = 0; s < SPW; s++) {
                int gcol = (wv * SPW + s) * 16 + m16;
                #pragma unroll
                for (int r = 0; r < 4; r++) {
                    int grow = rowbase + quad * 4 + r;
                    if (grow < 3 * M) Gout[(size_t)grow * NG + gcol] = ga[s][r];
                }
            }
        }
        __threadfence_block();
        __syncthreads();
    }

    // ---- stage 1: h = silu(A@W1 + b1) ----
    f32x4 acc1[2][2];
    #pragma unroll
    for (int s = 0; s < 2; s++)
        #pragma unroll
        for (int tm = 0; tm < 2; tm++) acc1[s][tm] = 0.0f;

    for (int kb = 0; kb < KB1; kb++) {
        int k0 = kb << 5;
        __syncthreads();
        {
            int r = tid >> 3, c4 = (tid & 7) << 2;
            int row = i0 + r;
            float4 v = {0.f, 0.f, 0.f, 0.f};
            if (row < M) {
                if (PRO == 0) {
                    v = *(const float4*)(A + (size_t)row * K1 + k0 + c4);
                } else {
                    int g = k0 + c4;
                    if (g < 128) {
                        v = *(const float4*)(A + (size_t)row * 128 + g);
                    } else {
                        int f = g - 128;
                        float4 v0 = *(const float4*)(mumix + ((size_t)row*3 + 0)*256 + f);
                        float4 v1 = *(const float4*)(mumix + ((size_t)row*3 + 1)*256 + f);
                        float4 v2 = *(const float4*)(mumix + ((size_t)row*3 + 2)*256 + f);
                        v.x = sqrtf(v0.x*v0.x + v1.x*v1.x + v2.x*v2.x + 1e-8f);
                        v.y = sqrtf(v0.y*v0.y + v1.y*v1.y + v2.y*v2.y + 1e-8f);
                        v.z = sqrtf(v0.z*v0.z + v1.z*v1.z + v2.z*v2.z + 1e-8f);
                        v.w = sqrtf(v0.w*v0.w + v1.w*v1.w + v2.w*v2.w + 1e-8f);
                    }
                }
            }
            unsigned short h0,l0,h1,l1,h2,l2,h3,l3;
            split_bf16(v.x, h0, l0); split_bf16(v.y, h1, l1);
            split_bf16(v.z, h2, l2); split_bf16(v.w, h3, l3);
            us4 hv = {h0, h1, h2, h3}, lv = {l0, l1, l2, l3};
            *(us4*)(A1h + r * 40 + c4) = hv;
            *(us4*)(A1l + r * 40 + c4) = lv;
        }
        __syncthreads();
        #pragma unroll
        for (int tm = 0; tm < 2; tm++) {
            short8 ah = *(const short8*)(A1h + (tm * 16 + m16) * 40 + quad * 8);
            short8 al = *(const short8*)(A1l + (tm * 16 + m16) * 40 + quad * 8);
            #pragma unroll
            for (int s = 0; s < 2; s++) {
                int sIdx = wv * 2 + s;
                size_t bofs = (((size_t)sIdx * KB1 + kb) * 64 + lane) * 8;
                short8 bh = *(const short8*)(B1h + bofs);
                short8 bl = *(const short8*)(B1l + bofs);
                acc1[s][tm] = __builtin_amdgcn_mfma_f32_16x16x32_bf16(ah, bh, acc1[s][tm], 0, 0, 0);
                acc1[s][tm] = __builtin_amdgcn_mfma_f32_16x16x32_bf16(ah, bl, acc1[s][tm], 0, 0, 0);
                acc1[s][tm] = __builtin_amdgcn_mfma_f32_16x16x32_bf16(al, bh, acc1[s][tm], 0, 0, 0);
            }
        }
    }
    __syncthreads();
    #pragma unroll
    for (int s = 0; s < 2; s++) {
        int col = wv * 32 + s * 16 + m16;
        float bb = b1[col];
        #pragma unroll
        for (int tm = 0; tm < 2; tm++) {
            #pragma unroll
            for (int r = 0; r < 4; r++) {
                int row = tm * 16 + quad * 4 + r;
                float v = silu_f(acc1[s][tm][r] + bb);
                unsigned short h, l;
                split_bf16(v, h, l);
                Hh[row * 136 + col] = h;
                Hl[row * 136 + col] = l;
            }
        }
    }
    __syncthreads();

    // ---- stage 2: h2 = h@W2 ----
    f32x4 acc2[S2][2];
    #pragma unroll
    for (int s = 0; s < S2; s++)
        #pragma unroll
        for (int tm = 0; tm < 2; tm++) acc2[s][tm] = 0.0f;

    #pragma unroll
    for (int kb = 0; kb < 4; kb++) {
        short8 ah[2], al[2];
        #pragma unroll
        for (int tm = 0; tm < 2; tm++) {
            ah[tm] = *(const short8*)(Hh + (tm * 16 + m16) * 136 + kb * 32 + quad * 8);
            al[tm] = *(const short8*)(Hl + (tm * 16 + m16) * 136 + kb * 32 + quad * 8);
        }
        #pragma unroll
        for (int s = 0; s < S2; s++) {
            int sIdx = wv * S2 + s;
            size_t bofs = (((size_t)sIdx * 4 + kb) * 64 + lane) * 8;
            short8 bh = *(const short8*)(B2h + bofs);
            short8 bl = *(const short8*)(B2l + bofs);
            #pragma unroll
            for (int tm = 0; tm < 2; tm++) {
                acc2[s][tm] = __builtin_amdgcn_mfma_f32_16x16x32_bf16(ah[tm], bh, acc2[s][tm], 0, 0, 0);
                acc2[s][tm] = __builtin_amdgcn_mfma_f32_16x16x32_bf16(ah[tm], bl, acc2[s][tm], 0, 0, 0);
                acc2[s][tm] = __builtin_amdgcn_mfma_f32_16x16x32_bf16(al[tm], bh, acc2[s][tm], 0, 0, 0);
            }
        }
    }

    if (EPI == 0) {
        #pragma unroll
        for (int s = 0; s < S2; s++) {
            int col = (wv * S2 + s) * 16 + m16;
            float bb = b2 ? b2[col] : 0.0f;
            #pragma unroll
            for (int tm = 0; tm < 2; tm++) {
                #pragma unroll
                for (int r = 0; r < 4; r++) {
                    int row = i0 + tm * 16 + quad * 4 + r;
                    if (row < M) C[(size_t)row * N2 + col] = acc2[s][tm][r] + bb;
                }
            }
        }
    } else if (EPI == 1) {
        #pragma unroll
        for (int s = 0; s < S2; s++) {
            int col = (wv * S2 + s) * 16 + m16;
            float bb = b2[col];
            #pragma unroll
            for (int tm = 0; tm < 2; tm++) {
                #pragma unroll
                for (int r = 0; r < 4; r++) {
                    int row = i0 + tm * 16 + quad * 4 + r;
                    if (row < M) {
                        float as = acc2[s][tm][r] + bb;
                        float E0 = Eat[row*3+0], E1 = Eat[row*3+1], E2 = Eat[row*3+2];
                        size_t b0 = ((size_t)row*3 + 0)*128 + col;
                        size_t b1o = ((size_t)row*3 + 1)*128 + col;
                        size_t b2o = ((size_t)row*3 + 2)*128 + col;
                        float a0 = av[b0], a1 = av[b1o], a2 = av[b2o];
                        float dot = a0*E0 + a1*E1 + a2*E2;
                        muRW[b0] += as*E0 - dot*a0;
                        muRW[b1o] += as*E1 - dot*a1;
                        muRW[b2o] += as*E2 - dot*a2;
                    }
                }
            }
        }
    } else {
        #pragma unroll
        for (int s = 0; s < S2; s++) {
            int col = (wv * S2 + s) * 16 + m16;
            float bb = b2[col];
            #pragma unroll
            for (int tm = 0; tm < 2; tm++) {
                #pragma unroll
                for (int r = 0; r < 4; r++) {
                    int row = tm * 16 + quad * 4 + r;
                    Ys[row * 384 + col] = acc2[s][tm][r] + bb;
                }
            }
        }
        __syncthreads();
        int f = tid & 127;
        #pragma unroll
        for (int it = 0; it < 16; it++) {
            int row = (tid >> 7) + it * 2;
            int i = i0 + row;
            if (i < M) {
                float yq  = Ys[row * 384 + f];
                float ym  = Ys[row * 384 + 128 + f];
                float yqm = Ys[row * 384 + 256 + f];
                float sdot = 0.0f;
                float W[3];
                #pragma unroll
                for (int d = 0; d < 3; d++) {
                    float Vd = mumix[((size_t)i*3 + d)*256 + f];
                    W[d]     = mumix[((size_t)i*3 + d)*256 + 128 + f];
                    sdot += Vd * W[d];
                }
                float qn = qRW[(size_t)i*128 + f] + yq + yqm * sdot;
                qRW[(size_t)i*128 + f] = qn;
                float mun[3];
                #pragma unroll
                for (int d = 0; d < 3; d++) {
                    size_t mo = ((size_t)i*3 + d)*128 + f;
                    mun[d] = muRW[mo] + ym * W[d];
                    muRW[mo] = mun[d];
                }
                if (last) {
                    outPk[(size_t)i*512 + f] = qn;
                    #pragma unroll
                    for (int d = 0; d < 3; d++)
                        outPk[(size_t)i*512 + 128 + d*128 + f] = mun[d];
                }
            }
        }
    }
}

// ---------------- edge aggregation: MFMA filter dots, 4 waves/block -------------
__global__ __launch_bounds__(256) void k_edgeM(
    int t, const float* __restrict__ phi_s, const float4* __restrict__ df_s,
    const int* __restrict__ j_s, const int* __restrict__ rowptr,
    const float* __restrict__ x, const float* __restrict__ mu_in,
    const unsigned short* __restrict__ wfh, const unsigned short* __restrict__ wfl,
    float* __restrict__ q, float* __restrict__ mu_out)
{
    int lane = threadIdx.x & 63;
    int g  = blockIdx.x * 4 + (threadIdx.x >> 6);
    int ia = g >> 1;
    int h  = g & 1;
    int col = lane & 15, quad = lane >> 4;

    int p0 = rowptr[ia], p1 = rowptr[ia + 1];

    float accq[4] = {};
    float accd[3][4] = {};

    for (int pb = p0; pb < p1; pb += 16) {
        int e = pb + col;
        bool val = (e < p1);
        int ec = val ? e : (p1 - 1);
        float av[8] = {0,0,0,0,0,0,0,0};
        if (val) {
            const float* pr = phi_s + (size_t)ec * 20;
            if (quad == 0) {
                float4 a = *(const float4*)(pr);
                float4 b = *(const float4*)(pr + 4);
                av[0]=a.x; av[1]=a.y; av[2]=a.z; av[3]=a.w;
                av[4]=b.x; av[5]=b.y; av[6]=b.z; av[7]=b.w;
            } else if (quad == 1) {
                float4 a = *(const float4*)(pr + 8);
                float4 b = *(const float4*)(pr + 12);
                av[0]=a.x; av[1]=a.y; av[2]=a.z; av[3]=a.w;
                av[4]=b.x; av[5]=b.y; av[6]=b.z; av[7]=b.w;
            } else if (quad == 2) {
                float4 a = *(const float4*)(pr + 16);
                av[0]=a.x; av[1]=a.y; av[2]=a.z; av[3]=a.w;
                av[4]=df_s[ec].w;               // k=20 -> fcut (bias row)
            }
        }
        short8 ah, al;
        #pragma unroll
        for (int j = 0; j < 8; j++) {
            unsigned short hh, ll;
            split_bf16(av[j], hh, ll);
            ah[j] = (short)hh; al[j] = (short)ll;
        }

        f32x4 dt[3][4];
        #pragma unroll
        for (int c = 0; c < 3; c++) {
            #pragma unroll
            for (int s = 0; s < 4; s++) {
                int st = c * 8 + h * 4 + s;
                size_t bo = (((size_t)(t * 24 + st)) * 64 + lane) * 8;
                short8 bh = *(const short8*)(wfh + bo);
                short8 bl = *(const short8*)(wfl + bo);
                f32x4 d = {0.f, 0.f, 0.f, 0.f};
                d = __builtin_amdgcn_mfma_f32_16x16x32_bf16(ah, bh, d, 0, 0, 0);
                d = __builtin_amdgcn_mfma_f32_16x16x32_bf16(ah, bl, d, 0, 0, 0);
                d = __builtin_amdgcn_mfma_f32_16x16x32_bf16(al, bh, d, 0, 0, 0);
                dt[c][s] = d;
            }
        }

        #pragma unroll
        for (int r = 0; r < 4; r++) {
            int pe = pb + quad * 4 + r;
            if (pe > p1 - 1) pe = p1 - 1;
            int j = j_s[pe];
            float4 dfr = df_s[pe];
            size_t xb = (size_t)j * 384 + h * 64 + col;
            size_t mb = (size_t)j * 384 + h * 64 + col;
            #pragma unroll
            for (int s = 0; s < 4; s++) {
                int o = s * 16;
                float xq  = x[xb + o];
                float xr_ = x[xb + 128 + o];
                float xm  = x[xb + 256 + o];
                float m0  = mu_in[mb + o];
                float m1  = mu_in[mb + 128 + o];
                float m2  = mu_in[mb + 256 + o];
                accq[s]    += dt[0][s][r] * xq;
                float xxr = dt[1][s][r] * xr_;
                float xxm = dt[2][s][r] * xm;
                accd[0][s] += xxr * dfr.x + xxm * m0;
                accd[1][s] += xxr * dfr.y + xxm * m1;
                accd[2][s] += xxr * dfr.z + xxm * m2;
            }
        }
    }

    #pragma unroll
    for (int s = 0; s < 4; s++) {
        accq[s] += __shfl_xor(accq[s], 16);
        accq[s] += __shfl_xor(accq[s], 32);
        #pragma unroll
        for (int d = 0; d < 3; d++) {
            accd[d][s] += __shfl_xor(accd[d][s], 16);
            accd[d][s] += __shfl_xor(accd[d][s], 32);
        }
    }
    if (quad == 0) {
        #pragma unroll
        for (int s = 0; s < 4; s++) {
            size_t qo = (size_t)ia * 128 + h * 64 + s * 16 + col;
            q[qo] += accq[s];
            #pragma unroll
            for (int d = 0; d < 3; d++) {
                size_t mo = ((size_t)ia * 3 + d) * 128 + h * 64 + s * 16 + col;
                mu_out[mo] = mu_in[mo] + accd[d][s];
            }
        }
    }
}

extern "C" void kernel_launch(void* const* d_in, const int* in_sizes, int n_in,
                              void* d_out, int out_size, void* d_ws, size_t ws_size,
                              hipStream_t stream)
{
    const int*   Z       = (const int*)d_in[0];
    const float* r_ij    = (const float*)d_in[1];
    const int*   idx_i   = (const int*)d_in[2];
    const int*   idx_j   = (const int*)d_in[3];
    const int*   idx_m   = (const int*)d_in[4];
    const float* e_field = (const float*)d_in[5];
    const float* emb     = (const float*)d_in[6];
    const float* filt_W  = (const float*)d_in[7];
    const float* filt_b  = (const float*)d_in[8];
    const float* iW1     = (const float*)d_in[9];
    const float* ib1     = (const float*)d_in[10];
    const float* iW2     = (const float*)d_in[11];
    const float* ib2     = (const float*)d_in[12];
    const float* sW1     = (const float*)d_in[13];
    const float* sb1     = (const float*)d_in[14];
    const float* sW2     = (const float*)d_in[15];
    const float* sb2     = (const float*)d_in[16];
    const float* vW      = (const float*)d_in[17];
    const float* mmW     = (const float*)d_in[18];
    const float* mW1     = (const float*)d_in[19];
    const float* mb1     = (const float*)d_in[20];
    const float* mW2     = (const float*)d_in[21];
    const float* mb2     = (const float*)d_in[22];
    float* out = (float*)d_out;

    float* base = (float*)d_ws;
    size_t off = 0;
    auto alloc = [&](size_t n) { float* p = base + off; off += (n + 255) & ~(size_t)255; return p; };
    float* q     = alloc((size_t)NA*128);
    float* mu_a  = alloc((size_t)NA*384);
    float* mu_b  = alloc((size_t)NA*384);
    float* s384  = alloc((size_t)NA*384);   // x, then a_v
    float* mumix = alloc((size_t)NA*768);
    float* Eat   = alloc((size_t)NA*3);
    float* phi_s = alloc((size_t)NE*20);
    float4* df_s = (float4*)alloc((size_t)NE*4);
    int* rowptr  = (int*)alloc(NA + 1);
    int* counts  = (int*)alloc(NA);
    int* cursor  = (int*)alloc(NA);
    int* j_s     = (int*)alloc(NE);
    unsigned short* wth = (unsigned short*)alloc(344064 + 256);
    unsigned short* wtl = (unsigned short*)alloc(344064 + 256);
    unsigned short* wfh = (unsigned short*)alloc(3*24*64*8/2 + 256);
    unsigned short* wfl = (unsigned short*)alloc(3*24*64*8/2 + 256);
    (void)ws_size; (void)in_sizes; (void)n_in; (void)out_size;

    WPack P;
    size_t woff = 0;
    unsigned short* WH[3][8];
    unsigned short* WL[3][8];
    int nw = 0;
    auto reg = [&](const float* src, int K, int N, int t, int slot) {
        P.w[nw].src = src; P.w[nw].dh = wth + woff; P.w[nw].dl = wtl + woff;
        P.w[nw].K = K; P.w[nw].N = N;
        WH[t][slot] = wth + woff; WL[t][slot] = wtl + woff;
        woff += (size_t)K * N; nw++;
    };
    for (int t = 0; t < 3; t++) {
        reg(iW1 + t*128*128, 128, 128, t, 0);
        reg(iW2 + t*128*384, 128, 384, t, 1);
        reg(sW1 + t*128*128, 128, 128, t, 2);
        reg(sW2 + t*128*128, 128, 128, t, 3);
        reg(vW  + t*128*128, 128, 128, t, 4);
        reg(mmW + t*128*256, 128, 256, t, 5);
        reg(mW1 + t*256*128, 256, 128, t, 6);
        reg(mW2 + t*128*384, 128, 384, t, 7);
    }

    k_wprep       <<<dim3(24, 24),          256, 0, stream>>>(P);
    k_wfprep      <<<18,                    256, 0, stream>>>(filt_W, filt_b, wfh, wfl);
    k_init        <<<(NA*384 + 255)/256,    256, 0, stream>>>(Z, idx_m, emb, e_field, q, mu_a, Eat, counts, cursor);
    k_count       <<<(NE + 255)/256,        256, 0, stream>>>(idx_i, counts);
    k_scan        <<<1,                     256, 0, stream>>>(counts, rowptr);
    k_geom_scatter<<<(NE + 255)/256,        256, 0, stream>>>(r_ij, idx_i, idx_j, rowptr, cursor,
                                                              phi_s, df_s, j_s);

    const int G32 = (NA + 31) / 32;       // 313
    float* mu_cur = mu_a;
    float* mu_nxt = mu_b;
    for (int t = 0; t < 3; t++) {
        // Interaction MLP: x = silu(q@iW1+b1)@iW2+b2
        k_mlp<128,384,0,0,0><<<G32, 256, 0, stream>>>(
            q, nullptr, WH[t][0], WL[t][0], ib1 + t*128, WH[t][1], WL[t][1], ib2 + t*384,
            nullptr, nullptr, nullptr,
            s384, nullptr, nullptr, nullptr, nullptr, nullptr, 0, NA);
        // edge message passing (owner-exclusive, MFMA filter dots)
        k_edgeM<<<NA/2, 256, 0, stream>>>(t, phi_s, df_s, j_s, rowptr, s384,
                                          mu_cur, wfh, wfl, q, mu_nxt);
        { float* tmp = mu_cur; mu_cur = mu_nxt; mu_nxt = tmp; }
        // FieldInteraction: PRE computes a_v = mu@vW per block; field epilogue
        k_mlp<128,128,0,1,1><<<G32, 256, 0, stream>>>(
            q, nullptr, WH[t][2], WL[t][2], sb1 + t*128, WH[t][3], WL[t][3], sb2 + t*128,
            WH[t][4], WL[t][4], s384,
            nullptr, s384, Eat, nullptr, mu_cur, nullptr, 0, NA);
        // Mixing: PRE computes mumix = mu@mmW per block; ctx prologue + mixupd
        k_mlp<256,384,1,2,2><<<G32, 256, 0, stream>>>(
            q, mumix, WH[t][6], WL[t][6], mb1 + t*128, WH[t][7], WL[t][7], mb2 + t*384,
            WH[t][5], WL[t][5], mumix,
            nullptr, nullptr, nullptr, q, mu_cur, out, (t == 2) ? 1 : 0, NA);
    }
}